// Round 1
// baseline (189.494 us; speedup 1.0000x reference)
//
#include <hip/hip_runtime.h>
#include <hip/hip_bf16.h>

// RPN loss: loss = (1/9) * [ BCE_sum(pred[:,0:18:2], target[:,0:1])
//                          + BCE_sum(pred[:,1:18:2], target[:,1:2]) ]
// pred:   (16, 54, 192, 192) fp32  -- only channels 0..17 are read
// target: (16,  6, 192, 192) fp32  -- only channels 0..1 are read
// loc:    (128, 2) int             -- UNUSED by the reference
// out:    1 fp32 scalar

#define HW_     (192 * 192)      // 36864
#define HW4_    (HW_ / 4)        // 9216 float4 per channel plane
#define NCH_    18               // channels of pred actually used
#define PREDC_  54               // pred channel stride count
#define TGTC_   6                // target channel stride count
#define NB_     16               // batch

__device__ __forceinline__ float bce_elem(float x, float y) {
    // max(x,0) - x*y + log1p(exp(-|x|))
    return fmaxf(x, 0.0f) - x * y + log1pf(__expf(-fabsf(x)));
}

__global__ __launch_bounds__(256) void rpn_bce_kernel(
        const float* __restrict__ pred,
        const float* __restrict__ target,
        float* __restrict__ out) {
    const int total = NB_ * NCH_ * HW4_;   // 2,654,208 float4 groups
    const int stride = gridDim.x * blockDim.x;

    const float4* __restrict__ p4 = (const float4*)pred;
    const float4* __restrict__ t4 = (const float4*)target;

    float acc = 0.0f;
    for (int i = blockIdx.x * blockDim.x + threadIdx.x; i < total; i += stride) {
        int b  = i / (NCH_ * HW4_);
        int r  = i - b * (NCH_ * HW4_);
        int c  = r / HW4_;
        int hw = r - c * HW4_;

        float4 x = p4[(b * PREDC_ + c) * HW4_ + hw];
        float4 y = t4[(b * TGTC_ + (c & 1)) * HW4_ + hw];

        acc += bce_elem(x.x, y.x);
        acc += bce_elem(x.y, y.y);
        acc += bce_elem(x.z, y.z);
        acc += bce_elem(x.w, y.w);
    }

    // wave-64 tree reduction
    #pragma unroll
    for (int off = 32; off > 0; off >>= 1)
        acc += __shfl_down(acc, off, 64);

    __shared__ float wsum[4];   // 256 threads / 64 lanes
    const int lane = threadIdx.x & 63;
    const int wid  = threadIdx.x >> 6;
    if (lane == 0) wsum[wid] = acc;
    __syncthreads();

    if (threadIdx.x == 0) {
        float s = wsum[0] + wsum[1] + wsum[2] + wsum[3];
        atomicAdd(out, s * (1.0f / 9.0f));
    }
}

extern "C" void kernel_launch(void* const* d_in, const int* in_sizes, int n_in,
                              void* d_out, int out_size, void* d_ws, size_t ws_size,
                              hipStream_t stream) {
    const float* pred   = (const float*)d_in[0];
    const float* target = (const float*)d_in[1];
    // d_in[2] (loc) unused by the reference computation.
    float* out = (float*)d_out;

    // d_out is poisoned to 0xAA before every launch — zero it first.
    hipMemsetAsync(out, 0, sizeof(float), stream);

    // 2048 blocks x 256 threads: ~5 float4 per thread grid-stride; plenty to
    // saturate 256 CUs on a streaming reduction.
    rpn_bce_kernel<<<2048, 256, 0, stream>>>(pred, target, out);
}